// Round 9
// baseline (203.363 us; speedup 1.0000x reference)
//
#include <hip/hip_runtime.h>

typedef unsigned short USH;
typedef short s16x8 __attribute__((ext_vector_type(8)));
typedef float f32x4 __attribute__((ext_vector_type(4)));
typedef float f32x4v __attribute__((ext_vector_type(4)));
typedef unsigned int u32x4 __attribute__((ext_vector_type(4)));
// may_alias variants for ALL type-punned LDS/global accesses.
typedef s16x8 s16x8_a __attribute__((may_alias));
typedef f32x4v f32x4v_a __attribute__((may_alias));
typedef u32x4 u32x4_a __attribute__((may_alias));
typedef unsigned long long u64_a __attribute__((may_alias));

#if __has_builtin(__builtin_amdgcn_exp2f)
#define EXP2F(x) __builtin_amdgcn_exp2f(x)  // raw v_exp_f32, no legalization
#else
#define EXP2F(x) __builtin_exp2f(x)
#endif

__device__ __forceinline__ USH f2bf(float f) {
  union { float f; unsigned int i; } c; c.f = f;
  unsigned int x = c.i;
  return (USH)((x + 0x7FFFu + ((x >> 16) & 1u)) >> 16);
}
__device__ __forceinline__ unsigned int pk_bf16(float a, float b) {
#if __has_builtin(__builtin_amdgcn_cvt_pk_bf16_f32)
  typedef USH ush2 __attribute__((ext_vector_type(2)));
  union { ush2 v; unsigned int u; } r;
  r.v = __builtin_amdgcn_cvt_pk_bf16_f32(a, b);
  return r.u;
#else
  union { float f; unsigned int i; } ca, cb; ca.f = a; cb.f = b;
  return ((ca.i + 0x8000u) >> 16) | ((cb.i + 0x8000u) & 0xFFFF0000u);
#endif
}

__device__ __forceinline__ f32x4 mfma16(s16x8 a, s16x8 b, f32x4 c) {
  return __builtin_amdgcn_mfma_f32_16x16x32_bf16(a, b, c, 0, 0, 0);
}

// async global->LDS, 16B per lane; LDS dest semantics: wave base + lane*16.
#if __has_builtin(__builtin_amdgcn_global_load_lds)
__device__ __forceinline__ void gld_lds16(const void* g, void* l) {
  __builtin_amdgcn_global_load_lds(
      static_cast<const unsigned int __attribute__((address_space(1)))*>(
          (const void __attribute__((address_space(1)))*)g),
      static_cast<unsigned int __attribute__((address_space(3)))*>(
          (void __attribute__((address_space(3)))*)l),
      16, 0, 0);
}
#else
__device__ __forceinline__ void gld_lds16(const void* g, void* l) {
  *(s16x8_a*)l = *(const s16x8_a*)g;  // fallback: synchronous copy, same addresses
}
#endif

// ------------- prep: WT[n][k] = bf16(W[k][n]) for the 4 weight matrices -------------
// (round-7: the x fp32->bf16 pass (z==4) is FUSED into gemm_bias MODE 1 --
//  total byte motion identical (192 MB either way, x is L3-resident), saves
//  the 96 MB prep pass (~13-15us) and one dispatch.)
__global__ __launch_bounds__(256) void prep(
    const float* __restrict__ Wq, const float* __restrict__ Wk,
    const float* __restrict__ Wv, const float* __restrict__ Wo,
    USH* __restrict__ wsT) {
  __shared__ float tile[32][33];
  const int z = blockIdx.z;
  const int t = threadIdx.x;
  const float* W = (z == 0) ? Wq : (z == 1) ? Wk : (z == 2) ? Wv : Wo;
  USH* WT = wsT + (size_t)z * 262144;
  const int n0 = blockIdx.x * 32, k0 = blockIdx.y * 32;
  const int tx = t & 31, ty = t >> 5;  // 32 x 8
  #pragma unroll
  for (int i = 0; i < 4; ++i)
    tile[ty + i * 8][tx] = W[(size_t)(k0 + ty + i * 8) * 512 + n0 + tx];
  __syncthreads();
  #pragma unroll
  for (int i = 0; i < 4; ++i)
    WT[(size_t)(n0 + ty + i * 8) * 512 + k0 + tx] = f2bf(tile[tx][ty + i * 8]);
}

// ---------------- GEMM v4: out = A[M,512] * WT^T + bias ----------------
// m97-proven single-buffer 2-barrier structure with global_load_lds staging,
// __syncthreads-only (deterministic; round-6 verified). XOR-swizzle
// both-sides (rule #21).
// MODE 0: A = att bf16; out float[m*512+n] (d_out fp32).
// MODE 1: A = x fp32 staged DIRECTLY (32 KB tile), converted to bf16 frags
//   in-register via cvt_pk (bit-identical to the old prep rounding).
//   z==0 -> Q bf16 [B,H,S,Hd] scaled by sc*log2e; z==1 -> K [B,H,S,Hd];
//   z==2 -> V [B,H,Hd,S] (pre-transposed for attn).
template <int MODE>
__global__ __launch_bounds__(256, 3) void gemm_bias(
    const USH* __restrict__ A, const float* __restrict__ A32,
    const USH* __restrict__ BT0,
    const float* __restrict__ b0, const float* __restrict__ b1,
    const float* __restrict__ b2,
    USH* __restrict__ oQ, USH* __restrict__ oKV, float* __restrict__ oF) {
  // MODE 1: As holds fp32 [128 rows][64 f32] (32 KB); MODE 0: bf16 [128][64] (16 KB)
  __shared__ __align__(16) USH As[MODE == 1 ? 16384 : 8192];
  __shared__ __align__(16) USH Bs[8192];  // [128 rows][64 USH] chunk-swizzled
  const int z = blockIdx.z;
  const USH* BT = BT0 + (size_t)z * 262144;
  const float* bias = (z == 0) ? b0 : ((z == 1) ? b1 : b2);
  USH* outb = (z == 0) ? oQ : (oKV + (size_t)(z - 1) * 4194304);
  const float qs = (MODE == 1 && z == 0) ? 0.06375871528132839f : 1.0f;

  const int t = threadIdx.x;
  const int w = t >> 6, lane = t & 63;
  const int c = lane & 15, g = lane >> 4;
  const int wm = w & 1, wn = w >> 1;
  const int m0 = blockIdx.x * 128, n0 = blockIdx.y * 128;

  f32x4 acc[4][4] = {};

  // --- B DMA mapping (bf16, 8 chunks/row): instr j covers rows w*32+j*8+(lane>>3),
  // phys chunk lane&7; source global chunk (lane&7)^(row&7).
  const int rB = w * 32 + (lane >> 3);                       // +j*8
  const int ccB = (((lane & 7) ^ ((lane >> 3) & 7))) * 8;
  const USH* BpD = BT + (size_t)(n0 + rB) * 512 + ccB;       // +kt*64 +j*4096
  USH* lB = Bs + w * 2048 + lane * 8;                        // +j*512

  // --- A DMA mapping ---
  // MODE 0 (bf16): same as B.
  const USH* ApD = nullptr;
  USH* lA0 = nullptr;
  // MODE 1 (fp32, 16 chunks/row of 4 f32): instr j covers rows j*16+w*4+(lane>>4),
  // phys chunk lane&15; source global chunk (lane&15)^(row&15).
  const float* Ap32 = nullptr;
  USH* lA1 = nullptr;
  if (MODE == 0) {
    ApD = A + (size_t)(m0 + rB) * 512 + ccB;
    lA0 = As + w * 2048 + lane * 8;
  } else {
    const int rA = w * 4 + (lane >> 4);                      // +j*16
    const int gcA = (lane & 15) ^ (rA & 15);                 // row&15 == rA&15 (j*16 ≡ 0)
    Ap32 = A32 + (size_t)(m0 + rA) * 512 + gcA * 4;          // +kt*64 +j*16*512
    lA1 = As + w * 512 + lane * 8;                           // +j*2048 (USH units)
  }

  for (int kt = 0; kt < 8; ++kt) {
    __syncthreads();  // full drain: previous COMPUTE's ds_reads done
    if (MODE == 0) {
      #pragma unroll
      for (int j = 0; j < 4; ++j) {
        gld_lds16(ApD + kt * 64 + j * 4096, lA0 + j * 512);
        gld_lds16(BpD + kt * 64 + j * 4096, lB + j * 512);
      }
    } else {
      #pragma unroll
      for (int j = 0; j < 8; ++j)   // A fp32: 32 KB
        gld_lds16(Ap32 + kt * 64 + (size_t)j * 8192, lA1 + j * 2048);
      #pragma unroll
      for (int j = 0; j < 4; ++j)
        gld_lds16(BpD + kt * 64 + j * 4096, lB + j * 512);
    }
    __syncthreads();  // full drain: DMA landed -> tile kt resident block-wide
    #pragma unroll
    for (int ks = 0; ks < 2; ++ks) {
      s16x8 af[4], bfr[4];
      #pragma unroll
      for (int i = 0; i < 4; ++i) {
        const int ra = wm * 64 + i * 16 + c;
        const int rb = wn * 64 + i * 16 + c;
        if (MODE == 0) {
          af[i] = *(const s16x8_a*)(As + ra * 64 + ((ks * 4 + g) ^ (ra & 7)) * 8);
        } else {
          const int e = ks * 4 + g;                 // 8-f32 group 0..7
          const int p0 = (2 * e) ^ (ra & 15), p1 = (2 * e + 1) ^ (ra & 15);
          const float* Af = (const float*)As + ra * 64;
          const f32x4v lo = *(const f32x4v_a*)(Af + p0 * 4);
          const f32x4v hi = *(const f32x4v_a*)(Af + p1 * 4);
          union { u32x4 u; s16x8 v; } cvt;
          cvt.u.x = pk_bf16(lo.x, lo.y); cvt.u.y = pk_bf16(lo.z, lo.w);
          cvt.u.z = pk_bf16(hi.x, hi.y); cvt.u.w = pk_bf16(hi.z, hi.w);
          af[i] = cvt.v;
        }
        bfr[i] = *(const s16x8_a*)(Bs + rb * 64 + ((ks * 4 + g) ^ (rb & 7)) * 8);
      }
      #pragma unroll
      for (int mf = 0; mf < 4; ++mf)
        #pragma unroll
        for (int nf = 0; nf < 4; ++nf)
          acc[mf][nf] = mfma16(af[mf], bfr[nf], acc[mf][nf]);
    }
  }

  #pragma unroll
  for (int nf = 0; nf < 4; ++nf) {
    const int n = n0 + wn * 64 + nf * 16 + c;
    const float bv = bias[n];
    #pragma unroll
    for (int mf = 0; mf < 4; ++mf)
      #pragma unroll
      for (int r = 0; r < 4; ++r) {
        const int m = m0 + wm * 64 + mf * 16 + g * 4 + r;
        const float v = (acc[mf][nf][r] + bv) * qs;
        if (MODE == 0) {
          oF[(size_t)m * 512 + n] = v;
        } else {
          const int bb = m >> 12, s = m & 4095, h = n >> 6, hd = n & 63;
          if (z == 2)
            outb[(((size_t)(bb * 8 + h)) * 64 + hd) * 4096 + s] = f2bf(v);
          else
            outb[(((size_t)(bb * 8 + h)) * 4096 + s) * 64 + hd] = f2bf(v);
        }
      }
  }
}

// ---------------- flash attention v14: KVBLK=128 (round-7 proven: 99.4us) ----------------
// Work-throughput-bound at ~700 TF effective (77% of the m214 plain-HIP attn
// ladder). Further gains need the full co-designed structure port (32x32
// swapped-QK, K-in-reg, in-register softmax) -- deferred; left as-is.
// 512 thr / 8 waves x 32 q-rows; grid (16 qt, 16 bh) = 256 blocks = 1/CU.
// LDS 135 KB; XOR-swizzled K/V; Ps wave-local; l = P.1 on the MFMA pipe;
// Q pre-scaled by sc*log2e; one __syncthreads per iter (deterministic).
__global__ __launch_bounds__(512, 2) void attn(const USH* __restrict__ Qbuf,
                                               const USH* __restrict__ kv,
                                               USH* __restrict__ att) {
  __shared__ __align__(16) USH Ks[2 * 8192];    // [buf][half][key 0..127][32 USH]
  __shared__ __align__(16) USH Vt[2 * 8192];    // [buf][64 hd][128 USH]
  __shared__ __align__(16) USH Ps[8][32 * 140]; // per-wave [32 qrow][140 key-pad]
  __shared__ float lbuf[8][32];

  const int t = threadIdx.x;
  const int w = t >> 6, lane = t & 63;
  const int c = lane & 15, g = lane >> 4;
  // XCD-aware remap, bijective on [0,256): each XCD owns bh {xcd, xcd+8}
  // -> KV working set 2 MB <= per-XCD L2.
  const int linear = blockIdx.x + (blockIdx.y << 4);
  const int xcd = linear & 7, idx = linear >> 3;   // idx in [0,32)
  const int bh = xcd + ((idx >> 4) << 3);
  const int bb = bh >> 3, hh = bh & 7;
  const size_t base = (size_t)bh * 262144;  // 4096*64
  const USH* Q = Qbuf + base;
  const USH* K = kv + base;                 // [S,Hd]
  const USH* V = kv + 4194304 + base;       // [Hd,S] (pre-transposed)
  const int q0 = (idx & 15) * 256 + w * 32;

  // Q fragments (B-operand of S^T): registers for the whole K loop
  s16x8 qf[2][2];  // [qi][kh]
  #pragma unroll
  for (int qi = 0; qi < 2; ++qi)
    #pragma unroll
    for (int kh = 0; kh < 2; ++kh)
      qf[qi][kh] = *(const s16x8_a*)(Q + (size_t)(q0 + qi * 16 + c) * 64 + kh * 32 + g * 8);

  // constant ones-column B-fragment: l = P . 1 on the MFMA pipe
  s16x8 onesf;
  {
    const short one = (short)0x3F80, val = (c == 0) ? one : (short)0;
    #pragma unroll
    for (int j = 0; j < 8; ++j) onesf[j] = val;
  }

  f32x4 o[2][4] = {};
  f32x4 o_l[2] = {};

  // --- DMA lane mappings (8 waves, 2 calls each per K and V per tile) ---
  const int keyK = w * 16 + (lane >> 2);               // 0..127
  const int ccK = (lane & 3) ^ ((keyK >> 1) & 3);
  const USH* gK0 = K + (size_t)keyK * 64 + ccK * 8;    // +kt*8192 +j*32
  const int hdV = w * 4 + (lane >> 4);                 // 0..31, +j*32
  const int ccV = (lane & 15) ^ (hdV & 7);
  const USH* gV0 = V + (size_t)hdV * 4096 + ccV * 8;   // +kt*128 +j*131072
  USH* lK = Ks + w * 512 + lane * 8;   // +buf*8192 +j*4096
  USH* lV = Vt + w * 512 + lane * 8;   // +buf*8192 +j*4096

  // issue tile 0 -> buf 0
  #pragma unroll
  for (int j = 0; j < 2; ++j) {
    gld_lds16(gK0 + j * 32, lK + j * 4096);
    gld_lds16(gV0 + (size_t)j * 131072, lV + j * 4096);
  }

  for (int kt = 0; kt < 32; ++kt) {
    const int buf = kt & 1;
    __syncthreads();  // implicit vmcnt(0): tile kt resident; buf^1 free
    if (kt < 31) {    // issue tile kt+1 -> buf^1; flies across this iteration
      const int nb = (buf ^ 1) * 8192;
      #pragma unroll
      for (int j = 0; j < 2; ++j) {
        gld_lds16(gK0 + (size_t)(kt + 1) * 8192 + j * 32, lK + nb + j * 4096);
        gld_lds16(gV0 + (size_t)(kt + 1) * 128 + (size_t)j * 131072, lV + nb + j * 4096);
      }
    }

    // S^T[key][qrow] = K * Q^T  (Q pre-scaled; st IS the exp2 argument)
    f32x4 st[2][8] = {};
    #pragma unroll
    for (int kh = 0; kh < 2; ++kh) {
      s16x8 ak[8];
      #pragma unroll
      for (int kff = 0; kff < 8; ++kff) {
        const int row = kff * 16 + c;
        const int qsw = (g ^ ((c >> 1) & 3)) * 8;
        ak[kff] = *(const s16x8_a*)(Ks + buf * 8192 + kh * 4096 + row * 32 + qsw);
      }
      #pragma unroll
      for (int qi = 0; qi < 2; ++qi)
        #pragma unroll
        for (int kff = 0; kff < 8; ++kff)
          st[qi][kff] = mfma16(ak[kff], qf[qi][kh], st[qi][kff]);
    }

    // p = exp2(s); pack; write P to Ps[w] (wave-local; in-order DS)
    #pragma unroll
    for (int qi = 0; qi < 2; ++qi)
      #pragma unroll
      for (int kff = 0; kff < 8; ++kff) {
        #pragma unroll
        for (int r = 0; r < 4; ++r) st[qi][kff][r] = EXP2F(st[qi][kff][r]);
        const unsigned int lo = pk_bf16(st[qi][kff][0], st[qi][kff][1]);
        const unsigned int hi = pk_bf16(st[qi][kff][2], st[qi][kff][3]);
        *(u64_a*)(&Ps[w][(qi * 16 + c) * 140 + kff * 16 + g * 4]) =
            (unsigned long long)lo | ((unsigned long long)hi << 32);
      }

    // O[qrow][hd] += P * V ; l[qrow] += P . 1
    #pragma unroll
    for (int kf = 0; kf < 4; ++kf) {
      s16x8 ap[2];
      #pragma unroll
      for (int qi = 0; qi < 2; ++qi)
        ap[qi] = *(const s16x8_a*)(&Ps[w][(qi * 16 + c) * 140 + kf * 32 + g * 8]);
      s16x8 bv[4];
      #pragma unroll
      for (int hf = 0; hf < 4; ++hf) {
        const int qv = (((kf * 4 + g) ^ (c & 7))) * 8;
        bv[hf] = *(const s16x8_a*)(Vt + buf * 8192 + (c + 16 * hf) * 128 + qv);
      }
      #pragma unroll
      for (int qi = 0; qi < 2; ++qi) {
        #pragma unroll
        for (int hf = 0; hf < 4; ++hf)
          o[qi][hf] = mfma16(ap[qi], bv[hf], o[qi][hf]);
        o_l[qi] = mfma16(ap[qi], onesf, o_l[qi]);
      }
    }
  }

  // l lives in lanes c==0 (D[m][0]); broadcast within the wave via LDS
  if (c == 0) {
    #pragma unroll
    for (int qi = 0; qi < 2; ++qi)
      #pragma unroll
      for (int r = 0; r < 4; ++r) lbuf[w][qi * 16 + g * 4 + r] = o_l[qi][r];
  }
  __syncthreads();

  #pragma unroll
  for (int qi = 0; qi < 2; ++qi)
    #pragma unroll
    for (int r = 0; r < 4; ++r) {
      const int ml = qi * 16 + g * 4 + r;
      const float linv = 1.0f / lbuf[w][ml];
      const int qrow = q0 + ml;
      #pragma unroll
      for (int hf = 0; hf < 4; ++hf) {
        const int hd = c + 16 * hf;
        att[((size_t)(bb * 4096 + qrow)) * 512 + hh * 64 + hd] =
            f2bf(o[qi][hf][r] * linv);
      }
    }
}

extern "C" void kernel_launch(void* const* d_in, const int* in_sizes, int n_in,
                              void* d_out, int out_size, void* d_ws, size_t ws_size,
                              hipStream_t stream) {
  (void)in_sizes; (void)n_in; (void)out_size; (void)ws_size;
  const float* x  = (const float*)d_in[0];
  const float* Wq = (const float*)d_in[1];
  const float* bq = (const float*)d_in[2];
  const float* Wk = (const float*)d_in[3];
  const float* bk = (const float*)d_in[4];
  const float* Wv = (const float*)d_in[5];
  const float* bv = (const float*)d_in[6];
  const float* Wo = (const float*)d_in[7];
  const float* bo = (const float*)d_in[8];
  USH* ws  = (USH*)d_ws;
  USH* wT  = ws;                       // 4 * 262144 bf16 transposed weights (2 MB)
  USH* kv  = ws + 1048576;             // K [B,H,S,Hd] + V [B,H,Hd,S] bf16 (16 MB)
  USH* att = ws + 1048576 + 8388608;   // 4194304 : attn out [B,S,D] bf16 (8 MB)
  float* outF = (float*)d_out;         // fp32 output (16 MB)
  USH* qscratch = (USH*)d_out;         // Q bf16 (8 MB), dead before final GEMM

  prep<<<dim3(16, 16, 4), 256, 0, stream>>>(Wq, Wk, Wv, Wo, wT);
  gemm_bias<1><<<dim3(64, 4, 3), 256, 0, stream>>>(nullptr, x, wT, bq, bk, bv,
                                                   qscratch, kv, nullptr);
  attn<<<dim3(16, 16), 512, 0, stream>>>(qscratch, kv, att);
  gemm_bias<0><<<dim3(64, 4, 1), 256, 0, stream>>>(att, nullptr, wT + 3 * 262144,
                                                   bo, bo, bo,
                                                   nullptr, nullptr, outF);
}